// Round 1
// baseline (455.539 us; speedup 1.0000x reference)
//
#include <hip/hip_runtime.h>
#include <math.h>
#include <limits.h>

#define BB 8
#define NN 9216
#define FF 1024
#define KK 4096
#define VOXINV_DIV 0.2f

// Workspace layout (ints):
//   keys     : BB*NN   (73728)
//   cnt      : BB*KK   (32768)
//   start    : BB*KK
//   slot2key : BB*KK
//   cursor   : BB*KK
//   counts   : BB
//   order    : BB*NN
// total ~1.1 MB

__global__ __launch_bounds__(1024) void k_hist(const float* __restrict__ xyz,
                                               int* __restrict__ keys,
                                               int* __restrict__ cnt,
                                               int* __restrict__ cursor) {
    const int b = blockIdx.x;
    const int t = threadIdx.x;
    __shared__ int s_cnt[KK];
    __shared__ int s_min[3 * 1024];
    const float* xb = xyz + (size_t)b * NN * 3;

    // Phase 1: per-axis min of floor(xyz/0.2)
    int m0 = INT_MAX, m1 = INT_MAX, m2 = INT_MAX;
    for (int p = t; p < NN; p += 1024) {
        int c0 = (int)floorf(xb[p * 3 + 0] / VOXINV_DIV);
        int c1 = (int)floorf(xb[p * 3 + 1] / VOXINV_DIV);
        int c2 = (int)floorf(xb[p * 3 + 2] / VOXINV_DIV);
        m0 = min(m0, c0); m1 = min(m1, c1); m2 = min(m2, c2);
    }
    s_min[t] = m0; s_min[1024 + t] = m1; s_min[2048 + t] = m2;
    __syncthreads();
    for (int off = 512; off > 0; off >>= 1) {
        if (t < off) {
            s_min[t]        = min(s_min[t],        s_min[t + off]);
            s_min[1024 + t] = min(s_min[1024 + t], s_min[1024 + t + off]);
            s_min[2048 + t] = min(s_min[2048 + t], s_min[2048 + t + off]);
        }
        __syncthreads();
    }
    const int mn0 = s_min[0], mn1 = s_min[1024], mn2 = s_min[2048];
    __syncthreads();

    // Phase 2: histogram compact keys
    for (int i = t; i < KK; i += 1024) s_cnt[i] = 0;
    __syncthreads();
    for (int p = t; p < NN; p += 1024) {
        int c0 = (int)floorf(xb[p * 3 + 0] / VOXINV_DIV) - mn0;
        int c1 = (int)floorf(xb[p * 3 + 1] / VOXINV_DIV) - mn1;
        int c2 = (int)floorf(xb[p * 3 + 2] / VOXINV_DIV) - mn2;
        c0 = min(max(c0, 0), 15);
        c1 = min(max(c1, 0), 15);
        c2 = min(max(c2, 0), 15);
        int key = (c0 << 8) | (c1 << 4) | c2;
        keys[(size_t)b * NN + p] = key;
        atomicAdd(&s_cnt[key], 1);
    }
    __syncthreads();
    for (int i = t; i < KK; i += 1024) {
        cnt[b * KK + i] = s_cnt[i];
        cursor[b * KK + i] = 0;
    }
}

__global__ __launch_bounds__(1024) void k_scan(const int* __restrict__ cnt,
                                               int* __restrict__ start,
                                               int* __restrict__ slot2key,
                                               int* __restrict__ counts) {
    const int b = blockIdx.x;
    const int t = threadIdx.x;
    __shared__ unsigned long long s_scan[1024];
    const int base = t * 4;
    int c[4];
    int to = 0, tc = 0;
    for (int j = 0; j < 4; j++) {
        c[j] = cnt[b * KK + base + j];
        to += (c[j] > 0);
        tc += c[j];
    }
    unsigned long long v = ((unsigned long long)(unsigned)to << 32) | (unsigned)tc;
    s_scan[t] = v;
    __syncthreads();
    for (int off = 1; off < 1024; off <<= 1) {
        unsigned long long add = (t >= off) ? s_scan[t - off] : 0ULL;
        __syncthreads();
        s_scan[t] += add;
        __syncthreads();
    }
    unsigned long long incl = s_scan[t];
    unsigned long long excl = incl - v;
    int rank = (int)(excl >> 32);
    int st   = (int)(excl & 0xffffffffULL);
    for (int j = 0; j < 4; j++) {
        start[b * KK + base + j] = st;
        if (c[j] > 0) {
            slot2key[b * KK + rank] = base + j;
            rank++;
        }
        st += c[j];
    }
    if (t == 1023) counts[b] = (int)(incl >> 32);
}

__global__ void k_offsets(const int* __restrict__ counts, float* __restrict__ out_off) {
    if (blockIdx.x == 0 && threadIdx.x == 0) {
        int cum = 0;
        for (int b = 0; b < BB; b++) {
            cum += counts[b];
            out_off[b] = (float)cum;
        }
    }
}

__global__ __launch_bounds__(256) void k_order(const int* __restrict__ keys,
                                               const int* __restrict__ start,
                                               int* __restrict__ cursor,
                                               int* __restrict__ order) {
    int p = blockIdx.x * 256 + threadIdx.x;
    if (p >= BB * NN) return;
    int b = p / NN;
    int lp = p - b * NN;
    int key = keys[p];
    int pos = atomicAdd(&cursor[b * KK + key], 1);
    order[(size_t)b * NN + start[b * KK + key] + pos] = lp;
}

__global__ __launch_bounds__(256) void k_pool(const float* __restrict__ feat,
                                              const int* __restrict__ cnt,
                                              const int* __restrict__ start,
                                              const int* __restrict__ slot2key,
                                              const int* __restrict__ order,
                                              const int* __restrict__ counts,
                                              float* __restrict__ out) {
    const int blk = blockIdx.x;          // b*KK + k
    const int b = blk >> 12;
    const int k = blk & (KK - 1);
    const int t = threadIdx.x;           // 256 threads, float4 each -> 1024 floats
    float4 acc = make_float4(0.f, 0.f, 0.f, 0.f);
    if (k < counts[b]) {
        int key = slot2key[b * KK + k];
        int c = cnt[b * KK + key];
        int s = start[b * KK + key];
        const float* fb = feat + (size_t)b * NN * FF;
        const int* ob = order + (size_t)b * NN + s;
        for (int i = 0; i < c; i++) {
            int p = ob[i];
            const float4* row = (const float4*)(fb + (size_t)p * FF);
            float4 vv = row[t];
            acc.x += vv.x; acc.y += vv.y; acc.z += vv.z; acc.w += vv.w;
        }
        float fc = (float)c;
        acc.x /= fc; acc.y /= fc; acc.z /= fc; acc.w /= fc;
    }
    float4* orow = (float4*)(out + (size_t)blk * FF);
    orow[t] = acc;
}

extern "C" void kernel_launch(void* const* d_in, const int* in_sizes, int n_in,
                              void* d_out, int out_size, void* d_ws, size_t ws_size,
                              hipStream_t stream) {
    const float* features = (const float*)d_in[0];   // (B, N, F) f32
    const float* xyz      = (const float*)d_in[1];   // (B, N, 3) f32
    float* out = (float*)d_out;                      // B*K*F pooled + B offsets (as f32)

    int* ws       = (int*)d_ws;
    int* keys     = ws;                              // B*N
    int* cnt      = keys     + BB * NN;              // B*K
    int* start    = cnt      + BB * KK;              // B*K
    int* slot2key = start    + BB * KK;              // B*K
    int* cursor   = slot2key + BB * KK;              // B*K
    int* counts   = cursor   + BB * KK;              // B
    int* order    = counts   + BB;                   // B*N

    k_hist<<<BB, 1024, 0, stream>>>(xyz, keys, cnt, cursor);
    k_scan<<<BB, 1024, 0, stream>>>(cnt, start, slot2key, counts);
    k_offsets<<<1, 64, 0, stream>>>(counts, out + (size_t)BB * KK * FF);
    k_order<<<(BB * NN + 255) / 256, 256, 0, stream>>>(keys, start, cursor, order);
    k_pool<<<BB * KK, 256, 0, stream>>>(features, cnt, start, slot2key, order, counts, out);
}

// Round 2
// 446.450 us; speedup vs baseline: 1.0204x; 1.0204x over previous
//
#include <hip/hip_runtime.h>
#include <math.h>

#define BB 8
#define NN 9216
#define FF 1024
#define KK 4096
#define VOX 0.2f

// Workspace layout (ints):
//   cnt       : BB*KK      }  zeroed together by one hipMemsetAsync
//   cursor    : BB*KK      }
//   keys      : BB*NN
//   start     : BB*KK
//   rank_info : BB*KK*2    (int2 {start, count} per compacted voxel rank)
//   counts    : BB
//   order     : BB*NN

__global__ __launch_bounds__(256) void k_hist(const float* __restrict__ xyz,
                                              int* __restrict__ keys,
                                              int* __restrict__ cnt) {
    int p = blockIdx.x * 256 + threadIdx.x;
    if (p >= BB * NN) return;
    int b = p / NN;
    const float* x = xyz + (size_t)p * 3;
    // Per-axis min subtraction in the reference shifts every key by a constant
    // per axis: grouping and lexicographic order are invariant, so skip it.
    int c0 = (int)floorf(x[0] / VOX);
    int c1 = (int)floorf(x[1] / VOX);
    int c2 = (int)floorf(x[2] / VOX);
    c0 = min(max(c0, 0), 15);
    c1 = min(max(c1, 0), 15);
    c2 = min(max(c2, 0), 15);
    int key = (c0 << 8) | (c1 << 4) | c2;
    keys[p] = key;
    atomicAdd(&cnt[b * KK + key], 1);
}

__global__ __launch_bounds__(1024) void k_scan(const int* __restrict__ cnt,
                                               int* __restrict__ start,
                                               int2* __restrict__ rank_info,
                                               int* __restrict__ counts) {
    const int b = blockIdx.x;
    const int t = threadIdx.x;
    __shared__ unsigned long long s_scan[1024];
    const int base = t * 4;
    int c[4];
    int to = 0, tc = 0;
    for (int j = 0; j < 4; j++) {
        c[j] = cnt[b * KK + base + j];
        to += (c[j] > 0);
        tc += c[j];
    }
    unsigned long long v = ((unsigned long long)(unsigned)to << 32) | (unsigned)tc;
    s_scan[t] = v;
    __syncthreads();
    for (int off = 1; off < 1024; off <<= 1) {
        unsigned long long add = (t >= off) ? s_scan[t - off] : 0ULL;
        __syncthreads();
        s_scan[t] += add;
        __syncthreads();
    }
    unsigned long long incl = s_scan[t];
    unsigned long long excl = incl - v;
    int rank = (int)(excl >> 32);
    int st   = (int)(excl & 0xffffffffULL);
    for (int j = 0; j < 4; j++) {
        start[b * KK + base + j] = st;
        if (c[j] > 0) {
            rank_info[b * KK + rank] = make_int2(st, c[j]);
            rank++;
        }
        st += c[j];
    }
    if (t == 1023) counts[b] = (int)(incl >> 32);
}

__global__ __launch_bounds__(256) void k_order(const int* __restrict__ keys,
                                               const int* __restrict__ start,
                                               int* __restrict__ cursor,
                                               int* __restrict__ order,
                                               const int* __restrict__ counts,
                                               float* __restrict__ out_off) {
    int p = blockIdx.x * 256 + threadIdx.x;
    if (p == 0) {  // counts[] is complete (k_scan precedes in stream order)
        int cum = 0;
        for (int b = 0; b < BB; b++) {
            cum += counts[b];
            out_off[b] = (float)cum;
        }
    }
    if (p >= BB * NN) return;
    int b = p / NN;
    int lp = p - b * NN;
    int key = keys[p];
    int pos = atomicAdd(&cursor[b * KK + key], 1);
    order[(size_t)b * NN + start[b * KK + key] + pos] = lp;
}

__global__ __launch_bounds__(256) void k_pool(const float* __restrict__ feat,
                                              const int2* __restrict__ rank_info,
                                              const int* __restrict__ order,
                                              const int* __restrict__ counts,
                                              float* __restrict__ out) {
    const int blk = blockIdx.x;          // b*KK + k
    const int b = blk >> 12;
    const int k = blk & (KK - 1);
    const int t = threadIdx.x;           // 256 threads * float4 = 1024 floats
    float4 a0 = make_float4(0.f, 0.f, 0.f, 0.f);
    float4 a1 = make_float4(0.f, 0.f, 0.f, 0.f);
    if (k < counts[b]) {
        int2 info = rank_info[(size_t)b * KK + k];
        const int s = info.x, c = info.y;
        const float* fb = feat + (size_t)b * NN * FF;
        const int* ob = order + (size_t)b * NN + s;
        int i = 0;
        for (; i + 1 < c; i += 2) {
            int p0 = ob[i], p1 = ob[i + 1];
            float4 v0 = ((const float4*)(fb + (size_t)p0 * FF))[t];
            float4 v1 = ((const float4*)(fb + (size_t)p1 * FF))[t];
            a0.x += v0.x; a0.y += v0.y; a0.z += v0.z; a0.w += v0.w;
            a1.x += v1.x; a1.y += v1.y; a1.z += v1.z; a1.w += v1.w;
        }
        if (i < c) {
            int p0 = ob[i];
            float4 v0 = ((const float4*)(fb + (size_t)p0 * FF))[t];
            a0.x += v0.x; a0.y += v0.y; a0.z += v0.z; a0.w += v0.w;
        }
        float fc = (float)c;
        a0.x = (a0.x + a1.x) / fc;
        a0.y = (a0.y + a1.y) / fc;
        a0.z = (a0.z + a1.z) / fc;
        a0.w = (a0.w + a1.w) / fc;
    }
    ((float4*)(out + (size_t)blk * FF))[t] = a0;
}

extern "C" void kernel_launch(void* const* d_in, const int* in_sizes, int n_in,
                              void* d_out, int out_size, void* d_ws, size_t ws_size,
                              hipStream_t stream) {
    const float* features = (const float*)d_in[0];   // (B, N, F) f32
    const float* xyz      = (const float*)d_in[1];   // (B, N, 3) f32
    float* out = (float*)d_out;                      // B*K*F pooled + B offsets (f32)

    int* ws        = (int*)d_ws;
    int* cnt       = ws;                             // B*K  } one memset
    int* cursor    = cnt    + BB * KK;               // B*K  }
    int* keys      = cursor + BB * KK;               // B*N
    int* start     = keys   + BB * NN;               // B*K
    int2* rankinfo = (int2*)(start + BB * KK);       // B*K int2
    int* counts    = (int*)(rankinfo + BB * KK);     // B
    int* order     = counts + BB;                    // B*N

    hipMemsetAsync(cnt, 0, 2 * BB * KK * sizeof(int), stream);
    k_hist<<<(BB * NN + 255) / 256, 256, 0, stream>>>(xyz, keys, cnt);
    k_scan<<<BB, 1024, 0, stream>>>(cnt, start, rankinfo, counts);
    k_order<<<(BB * NN + 255) / 256, 256, 0, stream>>>(keys, start, cursor, order,
                                                       counts, out + (size_t)BB * KK * FF);
    k_pool<<<BB * KK, 256, 0, stream>>>(features, rankinfo, order, counts, out);
}